// Round 21
// baseline (814.413 us; speedup 1.0000x reference)
//
#include <hip/hip_runtime.h>
#include <hip/hip_bf16.h>
#include <float.h>

#define OUT_CODES_OFF (33554432UL)            // 32768*1024
#define OUT_LOSS_OFF  (34603008UL)            // + 32768*32
#define TAU 1e-5f
#define INV_N (1.0f/33554432.0f)

typedef __attribute__((ext_vector_type(8))) short s16x8;
typedef __attribute__((ext_vector_type(4))) float f32x4;

__device__ __forceinline__ unsigned short bf16r(float x) {
    unsigned int u = __float_as_uint(x);
    unsigned int r = (u + 0x7FFFu + ((u >> 16) & 1u)) >> 16;
    return (unsigned short)r;
}
__device__ __forceinline__ float bf16f(unsigned short h) {
    return __uint_as_float(((unsigned int)h) << 16);
}
// truncation split: x = hi + lo with hi = trunc-bf16(x), lo = rnd-bf16(x - hi)
__device__ __forceinline__ void split8r(float4 v0, float4 v1, s16x8& h, s16x8& l) {
    float xs[8] = {v0.x, v0.y, v0.z, v0.w, v1.x, v1.y, v1.z, v1.w};
    #pragma unroll
    for (int e = 0; e < 8; ++e) {
        unsigned int u = __float_as_uint(xs[e]);
        unsigned short hh = (unsigned short)(u >> 16);
        h[e] = (short)hh;
        l[e] = (short)bf16r(xs[e] - bf16f(hh));
    }
}

__device__ __forceinline__ void gld16(const unsigned short* g, unsigned short* l) {
    __builtin_amdgcn_global_load_lds(
        (const __attribute__((address_space(1))) unsigned int*)g,
        (__attribute__((address_space(3))) unsigned int*)l, 16, 0, 0);
}

// ============ Prep: tile+split f32 matrix into chunked hi/lo bf16 tile pairs ========
__global__ void k_prep_split(const float* __restrict__ in,
                             unsigned short* __restrict__ ot)
{
    const int b = blockIdx.x, tid = threadIdx.x;
    const int rblk = b >> 5, kt = b & 31, r = tid >> 2, q = tid & 3;
    const float* src = in + (size_t)(rblk * 128 + r) * 1024 + kt * 32 + q * 8;
    float4 v0 = *(const float4*)src, v1 = *(const float4*)(src + 4);
    s16x8 h, l;
    split8r(v0, v1, h, l);
    unsigned short* dst = ot + (size_t)b * 8192 + q * 1024 + r * 8;
    *(s16x8*)dst = h;
    *(s16x8*)(dst + 4096) = l;
}

// ============ Prep: round f32 array to bf16 (rnd-to-nearest-even), 8 elems/thread ===
__global__ void k_prep_r(const float* __restrict__ in,
                         unsigned short* __restrict__ o,
                         int n8)
{
    const int i = blockIdx.x * 256 + threadIdx.x;
    if (i >= n8) return;
    const float4* p = (const float4*)(in + (size_t)i * 8);
    float4 v0 = p[0], v1 = p[1];
    float xs[8] = {v0.x, v0.y, v0.z, v0.w, v1.x, v1.y, v1.z, v1.w};
    s16x8 h;
    #pragma unroll
    for (int e = 0; e < 8; ++e) h[e] = (short)bf16r(xs[e]);
    *(s16x8*)(o + (size_t)i * 8) = h;
}

// ============ Kernel A: A reg-staged in-kernel (no prep_A), B via DMA; dbuf + XCD ===
// Schedule identical to R18: per it {ds_write A(it+1) + issue B DMA(it+1) into
// buf[(it+1)&1]; MFMA buf[it&1]; [screens]; tail __syncthreads}. LDS 99328 B.
__launch_bounds__(512, 1)
__global__ void k_enc_gl(const float* __restrict__ skills,
                         const unsigned short* __restrict__ Bt,
                         const float* __restrict__ enc_b,
                         const float* __restrict__ cb_g,
                         float* __restrict__ out)
{
    __shared__ __align__(16) unsigned short us[49664];   // 99328 B

    const int tid = threadIdx.x;
    const int wg = blockIdx.x;
    const int xcd = wg & 7, slot = wg >> 3;
    const int rb = xcd * 32 + (slot >> 1), chf = slot & 1;
    const int r0 = rb * 128;
    const int wid = tid >> 6, lane = tid & 63;
    const int wm = wid >> 1, wn = wid & 1;
    const int mbase = wm * 32;
    const int lhi = lane >> 4, llo = lane & 15;
    const int srow = tid >> 2, sq = tid & 3;

    if (tid < 256) {
        const float4* cr = (const float4*)&cb_g[tid * 32];
        float s = 0.f;
        #pragma unroll
        for (int i = 0; i < 8; ++i) {
            float4 v = cr[i];
            float c[4] = {v.x, v.y, v.z, v.w};
            #pragma unroll
            for (int e = 0; e < 4; ++e) {
                const int d = i * 4 + e, kc = d >> 3, e8 = d & 7;
                unsigned int u = __float_as_uint(c[e]);
                unsigned short hh = (unsigned short)(u >> 16);
                us[32768 + kc * 2048 + tid * 8 + e8] = hh;
                us[40960 + kc * 2048 + tid * 8 + e8] = bf16r(c[e] - bf16f(hh));
                s = fmaf(c[e], c[e], s);
            }
        }
        *(float*)&us[49152 + tid * 2] = s;
    }

    float4 ra0, ra1;
    // prologue: A(0) split -> buf0; B DMA(0) -> buf0; preload A(1) regs
    {
        const float* ap = &skills[(size_t)(r0 + srow) * 1024 + sq * 8];   // kt=0
        ra0 = *(const float4*)ap; ra1 = *(const float4*)(ap + 4);
        s16x8 h, l;
        split8r(ra0, ra1, h, l);
        *(s16x8*)&us[sq * 1024 + srow * 8] = h;
        *(s16x8*)&us[4096 + sq * 1024 + srow * 8] = l;
        const unsigned short* gB = Bt + ((size_t)((chf * 4 + 0) * 32 + 0)) * 8192 + tid * 8;
        gld16(gB,        us + 8192 + wid * 512);
        gld16(gB + 4096, us + 12288 + wid * 512);
        // A(1): it=1 -> nt=0, kt=1
        const float* ap1 = &skills[(size_t)(r0 + srow) * 1024 + 32 + sq * 8];
        ra0 = *(const float4*)ap1; ra1 = *(const float4*)(ap1 + 4);
    }
    __syncthreads();

    float vq_local = 0.f;
    f32x4 acc[2][4];
    const int ntg_base = chf * 4;

    for (int it = 0; it < 128; ++it) {
        const int nt = it >> 5, kt = it & 31;
        if (kt == 0) {
            #pragma unroll
            for (int mf = 0; mf < 2; ++mf)
                #pragma unroll
                for (int nf = 0; nf < 4; ++nf) acc[mf][nf] = (f32x4)0.f;
        }
        if (it < 127) {
            const int tt = it + 1, ntn = tt >> 5, ktn = tt & 31;
            const int nb = (tt & 1) * 16384;
            // A(it+1): split regs -> LDS (readers of this buffer finished last it)
            {
                s16x8 h, l;
                split8r(ra0, ra1, h, l);
                *(s16x8*)&us[nb + sq * 1024 + srow * 8] = h;
                *(s16x8*)&us[nb + 4096 + sq * 1024 + srow * 8] = l;
            }
            // B(it+1): DMA
            const unsigned short* gB = Bt + ((size_t)((ntg_base + ntn) * 32 + ktn)) * 8192 + tid * 8;
            gld16(gB,        us + nb + 8192 + wid * 512);
            gld16(gB + 4096, us + nb + 12288 + wid * 512);
            // A(it+2): global -> regs (hidden under MFMA)
            if (it < 126) {
                const int t2 = it + 2, kt2 = t2 & 31;
                const float* ap = &skills[(size_t)(r0 + srow) * 1024 + kt2 * 32 + sq * 8];
                ra0 = *(const float4*)ap; ra1 = *(const float4*)(ap + 4);
            }
        }
        {
            const int cb0 = (it & 1) * 16384;
            s16x8 ah[2], al[2];
            #pragma unroll
            for (int mf = 0; mf < 2; ++mf) {
                const int row = mbase + mf * 16 + llo;
                ah[mf] = *(s16x8*)&us[cb0 + lhi * 1024 + row * 8];
                al[mf] = *(s16x8*)&us[cb0 + 4096 + lhi * 1024 + row * 8];
            }
            #pragma unroll
            for (int nf = 0; nf < 4; ++nf) {
                const int rowb = wn * 64 + nf * 16 + llo;
                s16x8 bh = *(s16x8*)&us[cb0 + 8192 + lhi * 1024 + rowb * 8];
                s16x8 bl = *(s16x8*)&us[cb0 + 12288 + lhi * 1024 + rowb * 8];
                #pragma unroll
                for (int mf = 0; mf < 2; ++mf) {
                    acc[mf][nf] = __builtin_amdgcn_mfma_f32_16x16x32_bf16(ah[mf], bh, acc[mf][nf], 0, 0, 0);
                    acc[mf][nf] = __builtin_amdgcn_mfma_f32_16x16x32_bf16(ah[mf], bl, acc[mf][nf], 0, 0, 0);
                    acc[mf][nf] = __builtin_amdgcn_mfma_f32_16x16x32_bf16(al[mf], bh, acc[mf][nf], 0, 0, 0);
                }
            }
        }

        if (kt == 31) {
            for (int c = 0; c < 2; ++c) {
                __syncthreads();
                if (wn == c) {
                    #pragma unroll
                    for (int nf = 0; nf < 4; ++nf) {
                        const int colh = nf * 16 + llo;
                        const int tlc = colh >> 5, d = colh & 31;
                        const int kc = d >> 3, e8 = d & 7;
                        const float bias = enc_b[chf * 512 + nt * 128 + c * 64 + colh];
                        #pragma unroll
                        for (int mf = 0; mf < 2; ++mf)
                            #pragma unroll
                            for (int r = 0; r < 4; ++r) {
                                const int m_local = mbase + mf * 16 + lhi * 4 + r;
                                float val = acc[mf][nf][r] + bias;
                                unsigned int u = __float_as_uint(val);
                                unsigned short hh = (unsigned short)(u >> 16);
                                const int tok = m_local * 2 + tlc;
                                us[16384 + kc * 2048 + tok * 8 + e8] = hh;
                                us[24576 + kc * 2048 + tok * 8 + e8] = bf16r(val - bf16f(hh));
                            }
                    }
                }
                __syncthreads();
                s16x8 fh[2], fl[2];
                #pragma unroll
                for (int gi = 0; gi < 2; ++gi) {
                    const int tokrow = (wid * 2 + gi) * 16 + llo;
                    fh[gi] = *(s16x8*)&us[16384 + lhi * 2048 + tokrow * 8];
                    fl[gi] = *(s16x8*)&us[24576 + lhi * 2048 + tokrow * 8];
                }
                float s1[2][4], s2[2][4]; int bj[2][4];
                #pragma unroll
                for (int gi = 0; gi < 2; ++gi)
                    #pragma unroll
                    for (int r = 0; r < 4; ++r) { s1[gi][r] = FLT_MAX; s2[gi][r] = FLT_MAX; bj[gi][r] = 0; }
                for (int jb = 0; jb < 16; ++jb) {
                    const int j = jb * 16 + llo;
                    s16x8 ch = *(s16x8*)&us[32768 + lhi * 2048 + j * 8];
                    s16x8 cl = *(s16x8*)&us[40960 + lhi * 2048 + j * 8];
                    const float cnv = *(const float*)&us[49152 + j * 2];
                    #pragma unroll
                    for (int gi = 0; gi < 2; ++gi) {
                        f32x4 sc = (f32x4)0.f;
                        sc = __builtin_amdgcn_mfma_f32_16x16x32_bf16(fh[gi], ch, sc, 0, 0, 0);
                        sc = __builtin_amdgcn_mfma_f32_16x16x32_bf16(fh[gi], cl, sc, 0, 0, 0);
                        sc = __builtin_amdgcn_mfma_f32_16x16x32_bf16(fl[gi], ch, sc, 0, 0, 0);
                        #pragma unroll
                        for (int r = 0; r < 4; ++r) {
                            float s = fmaf(-2.f, sc[r], cnv);
                            if (s < s1[gi][r])      { s2[gi][r] = s1[gi][r]; s1[gi][r] = s; bj[gi][r] = j; }
                            else if (s < s2[gi][r]) { s2[gi][r] = s; }
                        }
                    }
                }
                #pragma unroll
                for (int gi = 0; gi < 2; ++gi) {
                    float Fp = 0.f;
                    #pragma unroll
                    for (int e = 0; e < 8; ++e) {
                        float fv = bf16f((unsigned short)fh[gi][e]) + bf16f((unsigned short)fl[gi][e]);
                        Fp = fmaf(fv, fv, Fp);
                    }
                    Fp += __shfl_xor(Fp, 16);
                    Fp += __shfl_xor(Fp, 32);
                    #pragma unroll
                    for (int r = 0; r < 4; ++r) {
                        float a1 = s1[gi][r], a2 = s2[gi][r]; int aj = bj[gi][r];
                        #pragma unroll
                        for (int off = 1; off <= 8; off <<= 1) {
                            float o1 = __shfl_xor(a1, off);
                            float o2 = __shfl_xor(a2, off);
                            int   oj = __shfl_xor(aj, off);
                            if (o1 < a1) { a2 = fminf(a1, o2); a1 = o1; aj = oj; }
                            else         { a2 = fminf(o1, a2); }
                        }
                        const float Ft = __shfl(Fp, lhi * 4 + r);
                        if (llo == 0) {
                            const int tok_local = (wid * 2 + gi) * 16 + lhi * 4 + r;
                            const int row = tok_local >> 1, tlc2 = tok_local & 1;
                            const int t = chf * 16 + nt * 4 + c * 2 + tlc2;
                            float cv = (a2 - a1 < TAU) ? (float)(aj + 512) : (float)aj;
                            out[OUT_CODES_OFF + (size_t)(r0 + row) * 32 + t] = cv;
                            vq_local += Ft + a1;
                        }
                    }
                }
            }
        }
        __syncthreads();
    }
    {
        float v = vq_local;
        #pragma unroll
        for (int off = 32; off >= 1; off >>= 1) v += __shfl_xor(v, off);
        if (lane == 0) atomicAdd(&out[OUT_LOSS_OFF], v * (1.25f * INV_N));
    }
}

// ============ Kernel A fallback (round-13 structure, proven) ========================
__launch_bounds__(512, 1)
__global__ void k_enc_fb(const float* __restrict__ skills,
                         const float* __restrict__ enc_w,
                         const float* __restrict__ enc_b,
                         const float* __restrict__ cb_g,
                         float* __restrict__ out)
{
    __shared__ __align__(16) unsigned short us[40960];

    const int tid = threadIdx.x;
    const int rb = blockIdx.x >> 1, chf = blockIdx.x & 1;
    const int r0 = rb * 128;
    const int wid = tid >> 6, lane = tid & 63;
    const int wm = wid >> 1, wn = wid & 1;
    const int mbase = wm * 32;
    const int lhi = lane >> 4, llo = lane & 15;
    const int srow = tid >> 2, sq = tid & 3;

    if (tid < 256) {
        const float4* cr = (const float4*)&cb_g[tid * 32];
        float s = 0.f;
        #pragma unroll
        for (int i = 0; i < 8; ++i) {
            float4 v = cr[i];
            float c[4] = {v.x, v.y, v.z, v.w};
            #pragma unroll
            for (int e = 0; e < 4; ++e) {
                const int d = i * 4 + e;
                unsigned int u = __float_as_uint(c[e]);
                unsigned short hh = (unsigned short)(u >> 16);
                us[20480 + tid * 40 + d] = hh;
                us[30720 + tid * 40 + d] = bf16r(c[e] - bf16f(hh));
                s = fmaf(c[e], c[e], s);
            }
        }
        *(float*)&us[20480 + tid * 40 + 32] = s;
    }
    __syncthreads();

    float vq_local = 0.f;
    f32x4 acc[2][4];
    float4 ra0, ra1, rb0, rb1;
    {
        const float* ap = &skills[(size_t)(r0 + srow) * 1024 + sq * 8];
        ra0 = *(const float4*)ap; ra1 = *(const float4*)(ap + 4);
        const float* bp = &enc_w[(size_t)(chf * 512 + srow) * 1024 + sq * 8];
        rb0 = *(const float4*)bp; rb1 = *(const float4*)(bp + 4);
    }

    for (int it = 0; it < 128; ++it) {
        const int nt = it >> 5, kt = it & 31;
        if (kt == 0) {
            #pragma unroll
            for (int mf = 0; mf < 2; ++mf)
                #pragma unroll
                for (int nf = 0; nf < 4; ++nf) acc[mf][nf] = (f32x4)0.f;
        }
        __syncthreads();
        {
            s16x8 h, l;
            split8r(ra0, ra1, h, l);
            *(s16x8*)&us[srow * 40 + sq * 8] = h;
            *(s16x8*)&us[5120 + srow * 40 + sq * 8] = l;
            split8r(rb0, rb1, h, l);
            *(s16x8*)&us[10240 + srow * 40 + sq * 8] = h;
            *(s16x8*)&us[15360 + srow * 40 + sq * 8] = l;
        }
        __syncthreads();
        if (it < 127) {
            const int it2 = it + 1, nt2 = it2 >> 5, kt2 = it2 & 31;
            const float* ap = &skills[(size_t)(r0 + srow) * 1024 + kt2 * 32 + sq * 8];
            ra0 = *(const float4*)ap; ra1 = *(const float4*)(ap + 4);
            const float* bp = &enc_w[(size_t)(chf * 512 + nt2 * 128 + srow) * 1024 + kt2 * 32 + sq * 8];
            rb0 = *(const float4*)bp; rb1 = *(const float4*)(bp + 4);
        }
        {
            s16x8 ah[2], al[2];
            #pragma unroll
            for (int mf = 0; mf < 2; ++mf) {
                const int row = mbase + mf * 16 + llo;
                ah[mf] = *(s16x8*)&us[row * 40 + lhi * 8];
                al[mf] = *(s16x8*)&us[5120 + row * 40 + lhi * 8];
            }
            #pragma unroll
            for (int nf = 0; nf < 4; ++nf) {
                const int rowb = wn * 64 + nf * 16 + llo;
                s16x8 bh = *(s16x8*)&us[10240 + rowb * 40 + lhi * 8];
                s16x8 bl = *(s16x8*)&us[15360 + rowb * 40 + lhi * 8];
                #pragma unroll
                for (int mf = 0; mf < 2; ++mf) {
                    acc[mf][nf] = __builtin_amdgcn_mfma_f32_16x16x32_bf16(ah[mf], bh, acc[mf][nf], 0, 0, 0);
                    acc[mf][nf] = __builtin_amdgcn_mfma_f32_16x16x32_bf16(ah[mf], bl, acc[mf][nf], 0, 0, 0);
                    acc[mf][nf] = __builtin_amdgcn_mfma_f32_16x16x32_bf16(al[mf], bh, acc[mf][nf], 0, 0, 0);
                }
            }
        }

        if (kt == 31) {
            for (int c = 0; c < 2; ++c) {
                __syncthreads();
                if (wn == c) {
                    #pragma unroll
                    for (int nf = 0; nf < 4; ++nf) {
                        const int colh = nf * 16 + llo;
                        const int tlc = colh >> 5, d = colh & 31;
                        const float bias = enc_b[chf * 512 + nt * 128 + c * 64 + colh];
                        #pragma unroll
                        for (int mf = 0; mf < 2; ++mf)
                            #pragma unroll
                            for (int r = 0; r < 4; ++r) {
                                const int m_local = mbase + mf * 16 + lhi * 4 + r;
                                float val = acc[mf][nf][r] + bias;
                                unsigned int u = __float_as_uint(val);
                                unsigned short hh = (unsigned short)(u >> 16);
                                const int tok = m_local * 2 + tlc;
                                us[tok * 40 + d] = hh;
                                us[10240 + tok * 40 + d] = bf16r(val - bf16f(hh));
                            }
                    }
                }
                __syncthreads();
                s16x8 fh[2], fl[2];
                #pragma unroll
                for (int gi = 0; gi < 2; ++gi) {
                    const int tokrow = (wid * 2 + gi) * 16 + llo;
                    fh[gi] = *(s16x8*)&us[tokrow * 40 + lhi * 8];
                    fl[gi] = *(s16x8*)&us[10240 + tokrow * 40 + lhi * 8];
                }
                float s1[2][4], s2[2][4]; int bj[2][4];
                #pragma unroll
                for (int gi = 0; gi < 2; ++gi)
                    #pragma unroll
                    for (int r = 0; r < 4; ++r) { s1[gi][r] = FLT_MAX; s2[gi][r] = FLT_MAX; bj[gi][r] = 0; }
                for (int jb = 0; jb < 16; ++jb) {
                    const int j = jb * 16 + llo;
                    s16x8 ch = *(s16x8*)&us[20480 + j * 40 + lhi * 8];
                    s16x8 cl = *(s16x8*)&us[30720 + j * 40 + lhi * 8];
                    const float cnv = *(const float*)&us[20480 + j * 40 + 32];
                    #pragma unroll
                    for (int gi = 0; gi < 2; ++gi) {
                        f32x4 sc = (f32x4)0.f;
                        sc = __builtin_amdgcn_mfma_f32_16x16x32_bf16(fh[gi], ch, sc, 0, 0, 0);
                        sc = __builtin_amdgcn_mfma_f32_16x16x32_bf16(fh[gi], cl, sc, 0, 0, 0);
                        sc = __builtin_amdgcn_mfma_f32_16x16x32_bf16(fl[gi], ch, sc, 0, 0, 0);
                        #pragma unroll
                        for (int r = 0; r < 4; ++r) {
                            float s = fmaf(-2.f, sc[r], cnv);
                            if (s < s1[gi][r])      { s2[gi][r] = s1[gi][r]; s1[gi][r] = s; bj[gi][r] = j; }
                            else if (s < s2[gi][r]) { s2[gi][r] = s; }
                        }
                    }
                }
                #pragma unroll
                for (int gi = 0; gi < 2; ++gi) {
                    float Fp = 0.f;
                    #pragma unroll
                    for (int e = 0; e < 8; ++e) {
                        float fv = bf16f((unsigned short)fh[gi][e]) + bf16f((unsigned short)fl[gi][e]);
                        Fp = fmaf(fv, fv, Fp);
                    }
                    Fp += __shfl_xor(Fp, 16);
                    Fp += __shfl_xor(Fp, 32);
                    #pragma unroll
                    for (int r = 0; r < 4; ++r) {
                        float a1 = s1[gi][r], a2 = s2[gi][r]; int aj = bj[gi][r];
                        #pragma unroll
                        for (int off = 1; off <= 8; off <<= 1) {
                            float o1 = __shfl_xor(a1, off);
                            float o2 = __shfl_xor(a2, off);
                            int   oj = __shfl_xor(aj, off);
                            if (o1 < a1) { a2 = fminf(a1, o2); a1 = o1; aj = oj; }
                            else         { a2 = fminf(o1, a2); }
                        }
                        const float Ft = __shfl(Fp, lhi * 4 + r);
                        if (llo == 0) {
                            const int tok_local = (wid * 2 + gi) * 16 + lhi * 4 + r;
                            const int row = tok_local >> 1, tlc2 = tok_local & 1;
                            const int t = chf * 16 + nt * 4 + c * 2 + tlc2;
                            float cv = (a2 - a1 < TAU) ? (float)(aj + 512) : (float)aj;
                            out[OUT_CODES_OFF + (size_t)(r0 + row) * 32 + t] = cv;
                            vq_local += Ft + a1;
                        }
                    }
                }
            }
        }
    }
    {
        float v = vq_local;
        #pragma unroll
        for (int off = 32; off >= 1; off >>= 1) v += __shfl_xor(v, off);
        if (lane == 0) atomicAdd(&out[OUT_LOSS_OFF], v * (1.25f * INV_N));
    }
}

// ============ Kernel F: wave-cooperative faithful numpy-f32 fixup (bit-identical) ===
__launch_bounds__(256)
__global__ void k_fix(const float* __restrict__ skills,
                      const float* __restrict__ enc_w,
                      const float* __restrict__ enc_b,
                      const float* __restrict__ cb_g,
                      float* __restrict__ codes)
{
    __shared__ unsigned int cnt;
    __shared__ unsigned short list[256];

    const int tid = threadIdx.x;
    const int base = blockIdx.x * 256;

    if (tid == 0) cnt = 0;
    __syncthreads();
    {
        const int c = (int)codes[base + tid];
        if (c >= 512) {
            unsigned int ix = atomicAdd(&cnt, 1u);
            list[ix] = (unsigned short)tid;
        }
    }
    __syncthreads();
    const unsigned int n = cnt;
    if (n == 0) return;

    const int wv = tid >> 6, lane = tid & 63;
    const int d = lane & 31;

    for (unsigned int i = wv; i < n; i += 4) {
        const int tok = base + (int)list[i];
        const int row = tok >> 5;
        const int t   = tok & 31;

        const float4* s4 = (const float4*)&skills[(size_t)row * 1024];
        const float4* w4 = (const float4*)&enc_w[(size_t)(t * 32 + d) * 1024];
        float v1 = 0.f, v2 = 0.f, v3 = 0.f;
        for (int q = 0; q < 96; ++q) {
            float4 a = s4[q], b = w4[q];
            v1 = fmaf(a.x, b.x, v1); v1 = fmaf(a.y, b.y, v1);
            v1 = fmaf(a.z, b.z, v1); v1 = fmaf(a.w, b.w, v1);
        }
        for (int q = 96; q < 192; ++q) {
            float4 a = s4[q], b = w4[q];
            v2 = fmaf(a.x, b.x, v2); v2 = fmaf(a.y, b.y, v2);
            v2 = fmaf(a.z, b.z, v2); v2 = fmaf(a.w, b.w, v2);
        }
        for (int q = 192; q < 256; ++q) {
            float4 a = s4[q], b = w4[q];
            v3 = fmaf(a.x, b.x, v3); v3 = fmaf(a.y, b.y, v3);
            v3 = fmaf(a.z, b.z, v3); v3 = fmaf(a.w, b.w, v3);
        }
        const float pd = ((v1 + v2) + v3) + enc_b[t * 32 + d];

        float pv[32];
        #pragma unroll
        for (int dd = 0; dd < 32; ++dd) pv[dd] = __shfl(pd, dd);

        float F;
        {
            float s[32];
            #pragma unroll
            for (int dd = 0; dd < 32; ++dd) s[dd] = pv[dd] * pv[dd];
            float r[8];
            #pragma unroll
            for (int j = 0; j < 8; ++j) r[j] = ((s[j] + s[8+j]) + s[16+j]) + s[24+j];
            F = ((r[0] + r[1]) + (r[2] + r[3])) + ((r[4] + r[5]) + (r[6] + r[7]));
        }

        float bs = FLT_MAX; int bj = 0;
        for (int m = 0; m < 4; ++m) {
            const int j = m * 64 + lane;
            const float* cj = &cb_g[j * 32];
            float g = 0.f;
            #pragma unroll
            for (int dd = 0; dd < 32; ++dd) g = fmaf(pv[dd], cj[dd], g);
            float cs[32];
            #pragma unroll
            for (int dd = 0; dd < 32; ++dd) cs[dd] = cj[dd] * cj[dd];
            float r[8];
            #pragma unroll
            for (int jj = 0; jj < 8; ++jj) r[jj] = ((cs[jj] + cs[8+jj]) + cs[16+jj]) + cs[24+jj];
            float cn = ((r[0] + r[1]) + (r[2] + r[3])) + ((r[4] + r[5]) + (r[6] + r[7]));
            float dist = (F - 2.0f * g) + cn;
            if (dist < bs) { bs = dist; bj = j; }
        }
        #pragma unroll
        for (int off = 32; off >= 1; off >>= 1) {
            float os = __shfl_xor(bs, off);
            int   oj = __shfl_xor(bj, off);
            if (os < bs || (os == bs && oj < bj)) { bs = os; bj = oj; }
        }
        if (lane == 0) codes[tok] = (float)bj;
    }
}

// ============ Kernel B: bf16 MFMA GEMM2, 2 t-steps per phase (R20) ==================
template <bool PRED>
__launch_bounds__(512)
__global__ void k_dec(const float* __restrict__ skills,
                      const float* __restrict__ cb_g,
                      const unsigned short* __restrict__ cbb,
                      const float* __restrict__ dec_w,
                      const unsigned short* __restrict__ dwb,
                      const float* __restrict__ dec_b,
                      const float* __restrict__ codes,
                      float* __restrict__ recon,
                      float* __restrict__ loss_out)
{
    __shared__ unsigned short Qt[2][128][40], Wt[2][128][40];   // 40 KB

    const int tid = threadIdx.x;
    const int r0 = (blockIdx.x >> 3) * 128;
    const int n0 = (blockIdx.x & 7) * 128;
    const int wid = tid >> 6, lane = tid & 63;
    const int wm = wid >> 1, wn = wid & 1;
    const int mbase = wm * 32, nbase = wn * 64;
    const int lhi = lane >> 4, llo = lane & 15;
    const int srow = tid >> 2, sq = tid & 3;

    f32x4 acc[2][4];
    #pragma unroll
    for (int mf = 0; mf < 2; ++mf)
        #pragma unroll
        for (int nf = 0; nf < 4; ++nf) acc[mf][nf] = (f32x4)0.f;

    s16x8 q16[2], w16[2];
    float4 q0[2], q1[2], w0[2], w1[2];

    #pragma unroll
    for (int ph = 0; ph < 2; ++ph) {
        const int cc = ((int)codes[(size_t)(r0 + srow) * 32 + ph]) & 255;
        if (PRED) {
            q16[ph] = *(const s16x8*)(cbb + cc * 32 + sq * 8);
            w16[ph] = *(const s16x8*)(dwb + (size_t)(n0 + srow) * 1024 + ph * 32 + sq * 8);
        } else {
            const float* cp = &cb_g[cc * 32 + sq * 8];
            q0[ph] = *(const float4*)cp; q1[ph] = *(const float4*)(cp + 4);
            const float* wp = &dec_w[(size_t)(n0 + srow) * 1024 + ph * 32 + sq * 8];
            w0[ph] = *(const float4*)wp; w1[ph] = *(const float4*)(wp + 4);
        }
    }

    for (int tt = 0; tt < 16; ++tt) {
        __syncthreads();
        #pragma unroll
        for (int ph = 0; ph < 2; ++ph) {
            if (PRED) {
                *(s16x8*)&Qt[ph][srow][sq * 8] = q16[ph];
                *(s16x8*)&Wt[ph][srow][sq * 8] = w16[ph];
            } else {
                float xs[8] = {q0[ph].x, q0[ph].y, q0[ph].z, q0[ph].w,
                               q1[ph].x, q1[ph].y, q1[ph].z, q1[ph].w};
                s16x8 h;
                #pragma unroll
                for (int e = 0; e < 8; ++e) h[e] = (short)bf16r(xs[e]);
                *(s16x8*)&Qt[ph][srow][sq * 8] = h;
                float ys[8] = {w0[ph].x, w0[ph].y, w0[ph].z, w0[ph].w,
                               w1[ph].x, w1[ph].y, w1[ph].z, w1[ph].w};
                #pragma unroll
                for (int e = 0; e < 8; ++e) h[e] = (short)bf16r(ys[e]);
                *(s16x8*)&Wt[ph][srow][sq * 8] = h;
            }
        }
        __syncthreads();
        if (tt < 15) {
            #pragma unroll
            for (int ph = 0; ph < 2; ++ph) {
                const int tn = tt * 2 + 2 + ph;
                const int cc = ((int)codes[(size_t)(r0 + srow) * 32 + tn]) & 255;
                if (PRED) {
                    q16[ph] = *(const s16x8*)(cbb + cc * 32 + sq * 8);
                    w16[ph] = *(const s16x8*)(dwb + (size_t)(n0 + srow) * 1024 + tn * 32 + sq * 8);
                } else {
                    const float* cp = &cb_g[cc * 32 + sq * 8];
                    q0[ph] = *(const float4*)cp; q1[ph] = *(const float4*)(cp + 4);
                    const float* wp = &dec_w[(size_t)(n0 + srow) * 1024 + tn * 32 + sq * 8];
                    w0[ph] = *(const float4*)wp; w1[ph] = *(const float4*)(wp + 4);
                }
            }
        }
        #pragma unroll
        for (int ph = 0; ph < 2; ++ph) {
            s16x8 aq[2], bw[4];
            #pragma unroll
            for (int mf = 0; mf < 2; ++mf)
                aq[mf] = *(s16x8*)&Qt[ph][mbase + mf * 16 + llo][lhi * 8];
            #pragma unroll
            for (int nf = 0; nf < 4; ++nf)
                bw[nf] = *(s16x8*)&Wt[ph][nbase + nf * 16 + llo][lhi * 8];
            #pragma unroll
            for (int mf = 0; mf < 2; ++mf)
                #pragma unroll
                for (int nf = 0; nf < 4; ++nf)
                    acc[mf][nf] = __builtin_amdgcn_mfma_f32_16x16x32_bf16(aq[mf], bw[nf], acc[mf][nf], 0, 0, 0);
        }
    }

    float lsum = 0.f;
    #pragma unroll
    for (int mf = 0; mf < 2; ++mf)
        #pragma unroll
        for (int nf = 0; nf < 4; ++nf) {
            const int col = n0 + nbase + nf * 16 + llo;
            const float bias = dec_b[col];
            #pragma unroll
            for (int r = 0; r < 4; ++r) {
                const int row = r0 + mbase + mf * 16 + lhi * 4 + r;
                float rv = acc[mf][nf][r] + bias;
                float dv = rv - skills[(size_t)row * 1024 + col];
                lsum = fmaf(dv, dv, lsum);
                recon[(size_t)row * 1024 + col] = rv;
            }
        }
    #pragma unroll
    for (int off = 32; off >= 1; off >>= 1) lsum += __shfl_xor(lsum, off);
    if (lane == 0) atomicAdd(loss_out, lsum * INV_N);
}

extern "C" void kernel_launch(void* const* d_in, const int* in_sizes, int n_in,
                              void* d_out, int out_size, void* d_ws, size_t ws_size,
                              hipStream_t stream)
{
    const float* skills = (const float*)d_in[0];
    const float* enc_w  = (const float*)d_in[1];
    const float* enc_b  = (const float*)d_in[2];
    const float* cbg    = (const float*)d_in[3];
    const float* dec_w  = (const float*)d_in[4];
    const float* dec_b  = (const float*)d_in[5];
    float* out = (float*)d_out;

    hipMemsetAsync(out + OUT_LOSS_OFF, 0, 4, stream);

    // ws layout (big path): B-tiles 4MB | dwb 2MB | cbb 16KB
    const size_t NEED_BIG = 4UL*1024*1024 + 2097152UL + 16384UL + 256UL;
    unsigned short* wsu16 = (unsigned short*)d_ws;

    if (ws_size >= NEED_BIG) {
        unsigned short* Btl = wsu16;                    // 2097152 u16
        unsigned short* dwb = wsu16 + 2097152UL;        // 1048576 u16
        unsigned short* cbb = wsu16 + 3145728UL;        // 8192 u16

        k_prep_split<<<dim3(256),  dim3(512), 0, stream>>>(enc_w, Btl);
        k_enc_gl<<<dim3(512), dim3(512), 0, stream>>>(skills, Btl, enc_b, cbg, out);
        k_fix<<<dim3(4096), dim3(256), 0, stream>>>(skills, enc_w, enc_b, cbg, out + OUT_CODES_OFF);
        k_prep_r<<<dim3(512), dim3(256), 0, stream>>>(dec_w, dwb, 131072);
        k_prep_r<<<dim3(4), dim3(256), 0, stream>>>(cbg, cbb, 1024);
        k_dec<true><<<dim3(2048), dim3(512), 0, stream>>>(skills, cbg, cbb, dec_w, dwb, dec_b,
                                                          out + OUT_CODES_OFF, out, out + OUT_LOSS_OFF);
    } else {
        k_enc_fb<<<dim3(512), dim3(512), 0, stream>>>(skills, enc_w, enc_b, cbg, out);
        k_fix<<<dim3(4096), dim3(256), 0, stream>>>(skills, enc_w, enc_b, cbg, out + OUT_CODES_OFF);
        const bool pred = (ws_size >= (2097152UL + 16384UL + 64UL));
        unsigned short* dwb = wsu16;
        unsigned short* cbb = wsu16 + 1048576UL;
        if (pred) {
            k_prep_r<<<dim3(512), dim3(256), 0, stream>>>(dec_w, dwb, 131072);
            k_prep_r<<<dim3(4), dim3(256), 0, stream>>>(cbg, cbb, 1024);
            k_dec<true><<<dim3(2048), dim3(512), 0, stream>>>(skills, cbg, cbb, dec_w, dwb, dec_b,
                                                              out + OUT_CODES_OFF, out, out + OUT_LOSS_OFF);
        } else {
            k_dec<false><<<dim3(2048), dim3(512), 0, stream>>>(skills, cbg, cbb, dec_w, dwb, dec_b,
                                                               out + OUT_CODES_OFF, out, out + OUT_LOSS_OFF);
        }
    }
}

// Round 22
// 802.576 us; speedup vs baseline: 1.0147x; 1.0147x over previous
//
#include <hip/hip_runtime.h>
#include <hip/hip_bf16.h>
#include <float.h>

#define OUT_CODES_OFF (33554432UL)            // 32768*1024
#define OUT_LOSS_OFF  (34603008UL)            // + 32768*32
#define TAU 1e-5f
#define INV_N (1.0f/33554432.0f)

typedef __attribute__((ext_vector_type(8))) short s16x8;
typedef __attribute__((ext_vector_type(4))) float f32x4;

__device__ __forceinline__ unsigned short bf16r(float x) {
    unsigned int u = __float_as_uint(x);
    unsigned int r = (u + 0x7FFFu + ((u >> 16) & 1u)) >> 16;
    return (unsigned short)r;
}
__device__ __forceinline__ float bf16f(unsigned short h) {
    return __uint_as_float(((unsigned int)h) << 16);
}
// truncation split: x = hi + lo with hi = trunc-bf16(x), lo = rnd-bf16(x - hi)
__device__ __forceinline__ void split8r(float4 v0, float4 v1, s16x8& h, s16x8& l) {
    float xs[8] = {v0.x, v0.y, v0.z, v0.w, v1.x, v1.y, v1.z, v1.w};
    #pragma unroll
    for (int e = 0; e < 8; ++e) {
        unsigned int u = __float_as_uint(xs[e]);
        unsigned short hh = (unsigned short)(u >> 16);
        h[e] = (short)hh;
        l[e] = (short)bf16r(xs[e] - bf16f(hh));
    }
}

__device__ __forceinline__ void gld16(const unsigned short* g, unsigned short* l) {
    __builtin_amdgcn_global_load_lds(
        (const __attribute__((address_space(1))) unsigned int*)g,
        (__attribute__((address_space(3))) unsigned int*)l, 16, 0, 0);
}

// ============ Prep helpers (also used standalone on the fallback path) ==============
__device__ __forceinline__ void prep_split_body(const float* in, unsigned short* ot,
                                                int b, int tid)
{
    const int rblk = b >> 5, kt = b & 31, r = tid >> 2, q = tid & 3;
    const float* src = in + (size_t)(rblk * 128 + r) * 1024 + kt * 32 + q * 8;
    float4 v0 = *(const float4*)src, v1 = *(const float4*)(src + 4);
    s16x8 h, l;
    split8r(v0, v1, h, l);
    unsigned short* dst = ot + (size_t)b * 8192 + q * 1024 + r * 8;
    *(s16x8*)dst = h;
    *(s16x8*)(dst + 4096) = l;
}
__device__ __forceinline__ void prep_round_body(const float* in, unsigned short* o,
                                                int i, int n8)
{
    if (i >= n8) return;
    const float4* p = (const float4*)(in + (size_t)i * 8);
    float4 v0 = p[0], v1 = p[1];
    float xs[8] = {v0.x, v0.y, v0.z, v0.w, v1.x, v1.y, v1.z, v1.w};
    s16x8 h;
    #pragma unroll
    for (int e = 0; e < 8; ++e) h[e] = (short)bf16r(xs[e]);
    *(s16x8*)(o + (size_t)i * 8) = h;
}

__global__ void k_prep_split(const float* __restrict__ in,
                             unsigned short* __restrict__ ot)
{
    prep_split_body(in, ot, blockIdx.x, threadIdx.x);
}

__global__ void k_prep_r(const float* __restrict__ in,
                         unsigned short* __restrict__ o,
                         int n8)
{
    prep_round_body(in, o, blockIdx.x * 256 + threadIdx.x, n8);
}

// ============ Fused prep: one launch does all four preps (block-range dispatch) =====
// [0,8192): split skills->Atl; [8192,8448): split enc_w->Btl;
// [8448,8704): round dec_w->dwb (512 thr/blk); [8704,8706): round cbg->cbb.
__global__ void k_prep_all(const float* __restrict__ skills, unsigned short* __restrict__ Atl,
                           const float* __restrict__ enc_w,  unsigned short* __restrict__ Btl,
                           const float* __restrict__ dec_w,  unsigned short* __restrict__ dwb,
                           const float* __restrict__ cbg,    unsigned short* __restrict__ cbb)
{
    const int b = blockIdx.x, tid = threadIdx.x;
    if (b < 8192) {
        prep_split_body(skills, Atl, b, tid);
    } else if (b < 8448) {
        prep_split_body(enc_w, Btl, b - 8192, tid);
    } else if (b < 8704) {
        prep_round_body(dec_w, dwb, (b - 8448) * 512 + tid, 131072);
    } else {
        prep_round_body(cbg, cbb, (b - 8704) * 512 + tid, 1024);
    }
}

// ============ Kernel A (global_load_lds + 2-phase dbuf + XCD swizzle) — proven ======
__launch_bounds__(512, 1)
__global__ void k_enc_gl(const unsigned short* __restrict__ At,
                         const unsigned short* __restrict__ Bt,
                         const float* __restrict__ enc_b,
                         const float* __restrict__ cb_g,
                         float* __restrict__ out)
{
    __shared__ __align__(16) unsigned short us[49664];   // 99328 B

    const int tid = threadIdx.x;
    const int wg = blockIdx.x;
    const int xcd = wg & 7, slot = wg >> 3;
    const int rb = xcd * 32 + (slot >> 1), chf = slot & 1;
    const int r0 = rb * 128;
    const int wid = tid >> 6, lane = tid & 63;
    const int wm = wid >> 1, wn = wid & 1;
    const int mbase = wm * 32;
    const int lhi = lane >> 4, llo = lane & 15;

    if (tid < 256) {
        const float4* cr = (const float4*)&cb_g[tid * 32];
        float s = 0.f;
        #pragma unroll
        for (int i = 0; i < 8; ++i) {
            float4 v = cr[i];
            float c[4] = {v.x, v.y, v.z, v.w};
            #pragma unroll
            for (int e = 0; e < 4; ++e) {
                const int d = i * 4 + e, kc = d >> 3, e8 = d & 7;
                unsigned int u = __float_as_uint(c[e]);
                unsigned short hh = (unsigned short)(u >> 16);
                us[32768 + kc * 2048 + tid * 8 + e8] = hh;
                us[40960 + kc * 2048 + tid * 8 + e8] = bf16r(c[e] - bf16f(hh));
                s = fmaf(c[e], c[e], s);
            }
        }
        *(float*)&us[49152 + tid * 2] = s;
    }
    {
        const unsigned short* gA = At + ((size_t)(rb * 32 + 0)) * 8192 + tid * 8;
        const unsigned short* gB = Bt + ((size_t)((chf * 4 + 0) * 32 + 0)) * 8192 + tid * 8;
        gld16(gA,        us + wid * 512);
        gld16(gA + 4096, us + 4096 + wid * 512);
        gld16(gB,        us + 8192 + wid * 512);
        gld16(gB + 4096, us + 12288 + wid * 512);
    }
    __syncthreads();

    float vq_local = 0.f;
    f32x4 acc[2][4];
    const int ntg_base = chf * 4;

    for (int it = 0; it < 128; ++it) {
        const int nt = it >> 5, kt = it & 31;
        if (kt == 0) {
            #pragma unroll
            for (int mf = 0; mf < 2; ++mf)
                #pragma unroll
                for (int nf = 0; nf < 4; ++nf) acc[mf][nf] = (f32x4)0.f;
        }
        if (it < 127) {
            const int tt = it + 1, ntn = tt >> 5, ktn = tt & 31;
            const int nb = (tt & 1) * 16384;
            const unsigned short* gA = At + ((size_t)(rb * 32 + ktn)) * 8192 + tid * 8;
            const unsigned short* gB = Bt + ((size_t)((ntg_base + ntn) * 32 + ktn)) * 8192 + tid * 8;
            gld16(gA,        us + nb + wid * 512);
            gld16(gA + 4096, us + nb + 4096 + wid * 512);
            gld16(gB,        us + nb + 8192 + wid * 512);
            gld16(gB + 4096, us + nb + 12288 + wid * 512);
        }
        {
            const int cb0 = (it & 1) * 16384;
            s16x8 ah[2], al[2];
            #pragma unroll
            for (int mf = 0; mf < 2; ++mf) {
                const int row = mbase + mf * 16 + llo;
                ah[mf] = *(s16x8*)&us[cb0 + lhi * 1024 + row * 8];
                al[mf] = *(s16x8*)&us[cb0 + 4096 + lhi * 1024 + row * 8];
            }
            #pragma unroll
            for (int nf = 0; nf < 4; ++nf) {
                const int rowb = wn * 64 + nf * 16 + llo;
                s16x8 bh = *(s16x8*)&us[cb0 + 8192 + lhi * 1024 + rowb * 8];
                s16x8 bl = *(s16x8*)&us[cb0 + 12288 + lhi * 1024 + rowb * 8];
                #pragma unroll
                for (int mf = 0; mf < 2; ++mf) {
                    acc[mf][nf] = __builtin_amdgcn_mfma_f32_16x16x32_bf16(ah[mf], bh, acc[mf][nf], 0, 0, 0);
                    acc[mf][nf] = __builtin_amdgcn_mfma_f32_16x16x32_bf16(ah[mf], bl, acc[mf][nf], 0, 0, 0);
                    acc[mf][nf] = __builtin_amdgcn_mfma_f32_16x16x32_bf16(al[mf], bh, acc[mf][nf], 0, 0, 0);
                }
            }
        }

        if (kt == 31) {
            for (int c = 0; c < 2; ++c) {
                __syncthreads();
                if (wn == c) {
                    #pragma unroll
                    for (int nf = 0; nf < 4; ++nf) {
                        const int colh = nf * 16 + llo;
                        const int tlc = colh >> 5, d = colh & 31;
                        const int kc = d >> 3, e8 = d & 7;
                        const float bias = enc_b[chf * 512 + nt * 128 + c * 64 + colh];
                        #pragma unroll
                        for (int mf = 0; mf < 2; ++mf)
                            #pragma unroll
                            for (int r = 0; r < 4; ++r) {
                                const int m_local = mbase + mf * 16 + lhi * 4 + r;
                                float val = acc[mf][nf][r] + bias;
                                unsigned int u = __float_as_uint(val);
                                unsigned short hh = (unsigned short)(u >> 16);
                                const int tok = m_local * 2 + tlc;
                                us[16384 + kc * 2048 + tok * 8 + e8] = hh;
                                us[24576 + kc * 2048 + tok * 8 + e8] = bf16r(val - bf16f(hh));
                            }
                    }
                }
                __syncthreads();
                s16x8 fh[2], fl[2];
                #pragma unroll
                for (int gi = 0; gi < 2; ++gi) {
                    const int tokrow = (wid * 2 + gi) * 16 + llo;
                    fh[gi] = *(s16x8*)&us[16384 + lhi * 2048 + tokrow * 8];
                    fl[gi] = *(s16x8*)&us[24576 + lhi * 2048 + tokrow * 8];
                }
                float s1[2][4], s2[2][4]; int bj[2][4];
                #pragma unroll
                for (int gi = 0; gi < 2; ++gi)
                    #pragma unroll
                    for (int r = 0; r < 4; ++r) { s1[gi][r] = FLT_MAX; s2[gi][r] = FLT_MAX; bj[gi][r] = 0; }
                for (int jb = 0; jb < 16; ++jb) {
                    const int j = jb * 16 + llo;
                    s16x8 ch = *(s16x8*)&us[32768 + lhi * 2048 + j * 8];
                    s16x8 cl = *(s16x8*)&us[40960 + lhi * 2048 + j * 8];
                    const float cnv = *(const float*)&us[49152 + j * 2];
                    #pragma unroll
                    for (int gi = 0; gi < 2; ++gi) {
                        f32x4 sc = (f32x4)0.f;
                        sc = __builtin_amdgcn_mfma_f32_16x16x32_bf16(fh[gi], ch, sc, 0, 0, 0);
                        sc = __builtin_amdgcn_mfma_f32_16x16x32_bf16(fh[gi], cl, sc, 0, 0, 0);
                        sc = __builtin_amdgcn_mfma_f32_16x16x32_bf16(fl[gi], ch, sc, 0, 0, 0);
                        #pragma unroll
                        for (int r = 0; r < 4; ++r) {
                            float s = fmaf(-2.f, sc[r], cnv);
                            if (s < s1[gi][r])      { s2[gi][r] = s1[gi][r]; s1[gi][r] = s; bj[gi][r] = j; }
                            else if (s < s2[gi][r]) { s2[gi][r] = s; }
                        }
                    }
                }
                #pragma unroll
                for (int gi = 0; gi < 2; ++gi) {
                    float Fp = 0.f;
                    #pragma unroll
                    for (int e = 0; e < 8; ++e) {
                        float fv = bf16f((unsigned short)fh[gi][e]) + bf16f((unsigned short)fl[gi][e]);
                        Fp = fmaf(fv, fv, Fp);
                    }
                    Fp += __shfl_xor(Fp, 16);
                    Fp += __shfl_xor(Fp, 32);
                    #pragma unroll
                    for (int r = 0; r < 4; ++r) {
                        float a1 = s1[gi][r], a2 = s2[gi][r]; int aj = bj[gi][r];
                        #pragma unroll
                        for (int off = 1; off <= 8; off <<= 1) {
                            float o1 = __shfl_xor(a1, off);
                            float o2 = __shfl_xor(a2, off);
                            int   oj = __shfl_xor(aj, off);
                            if (o1 < a1) { a2 = fminf(a1, o2); a1 = o1; aj = oj; }
                            else         { a2 = fminf(o1, a2); }
                        }
                        const float Ft = __shfl(Fp, lhi * 4 + r);
                        if (llo == 0) {
                            const int tok_local = (wid * 2 + gi) * 16 + lhi * 4 + r;
                            const int row = tok_local >> 1, tlc2 = tok_local & 1;
                            const int t = chf * 16 + nt * 4 + c * 2 + tlc2;
                            float cv = (a2 - a1 < TAU) ? (float)(aj + 512) : (float)aj;
                            out[OUT_CODES_OFF + (size_t)(r0 + row) * 32 + t] = cv;
                            vq_local += Ft + a1;
                        }
                    }
                }
            }
        }
        __syncthreads();
    }
    {
        float v = vq_local;
        #pragma unroll
        for (int off = 32; off >= 1; off >>= 1) v += __shfl_xor(v, off);
        if (lane == 0) atomicAdd(&out[OUT_LOSS_OFF], v * (1.25f * INV_N));
    }
}

// ============ Kernel A fallback (round-13 structure, proven) ========================
__launch_bounds__(512, 1)
__global__ void k_enc_fb(const float* __restrict__ skills,
                         const float* __restrict__ enc_w,
                         const float* __restrict__ enc_b,
                         const float* __restrict__ cb_g,
                         float* __restrict__ out)
{
    __shared__ __align__(16) unsigned short us[40960];

    const int tid = threadIdx.x;
    const int rb = blockIdx.x >> 1, chf = blockIdx.x & 1;
    const int r0 = rb * 128;
    const int wid = tid >> 6, lane = tid & 63;
    const int wm = wid >> 1, wn = wid & 1;
    const int mbase = wm * 32;
    const int lhi = lane >> 4, llo = lane & 15;
    const int srow = tid >> 2, sq = tid & 3;

    if (tid < 256) {
        const float4* cr = (const float4*)&cb_g[tid * 32];
        float s = 0.f;
        #pragma unroll
        for (int i = 0; i < 8; ++i) {
            float4 v = cr[i];
            float c[4] = {v.x, v.y, v.z, v.w};
            #pragma unroll
            for (int e = 0; e < 4; ++e) {
                const int d = i * 4 + e;
                unsigned int u = __float_as_uint(c[e]);
                unsigned short hh = (unsigned short)(u >> 16);
                us[20480 + tid * 40 + d] = hh;
                us[30720 + tid * 40 + d] = bf16r(c[e] - bf16f(hh));
                s = fmaf(c[e], c[e], s);
            }
        }
        *(float*)&us[20480 + tid * 40 + 32] = s;
    }
    __syncthreads();

    float vq_local = 0.f;
    f32x4 acc[2][4];
    float4 ra0, ra1, rb0, rb1;
    {
        const float* ap = &skills[(size_t)(r0 + srow) * 1024 + sq * 8];
        ra0 = *(const float4*)ap; ra1 = *(const float4*)(ap + 4);
        const float* bp = &enc_w[(size_t)(chf * 512 + srow) * 1024 + sq * 8];
        rb0 = *(const float4*)bp; rb1 = *(const float4*)(bp + 4);
    }

    for (int it = 0; it < 128; ++it) {
        const int nt = it >> 5, kt = it & 31;
        if (kt == 0) {
            #pragma unroll
            for (int mf = 0; mf < 2; ++mf)
                #pragma unroll
                for (int nf = 0; nf < 4; ++nf) acc[mf][nf] = (f32x4)0.f;
        }
        __syncthreads();
        {
            s16x8 h, l;
            split8r(ra0, ra1, h, l);
            *(s16x8*)&us[srow * 40 + sq * 8] = h;
            *(s16x8*)&us[5120 + srow * 40 + sq * 8] = l;
            split8r(rb0, rb1, h, l);
            *(s16x8*)&us[10240 + srow * 40 + sq * 8] = h;
            *(s16x8*)&us[15360 + srow * 40 + sq * 8] = l;
        }
        __syncthreads();
        if (it < 127) {
            const int it2 = it + 1, nt2 = it2 >> 5, kt2 = it2 & 31;
            const float* ap = &skills[(size_t)(r0 + srow) * 1024 + kt2 * 32 + sq * 8];
            ra0 = *(const float4*)ap; ra1 = *(const float4*)(ap + 4);
            const float* bp = &enc_w[(size_t)(chf * 512 + nt2 * 128 + srow) * 1024 + kt2 * 32 + sq * 8];
            rb0 = *(const float4*)bp; rb1 = *(const float4*)(bp + 4);
        }
        {
            s16x8 ah[2], al[2];
            #pragma unroll
            for (int mf = 0; mf < 2; ++mf) {
                const int row = mbase + mf * 16 + llo;
                ah[mf] = *(s16x8*)&us[row * 40 + lhi * 8];
                al[mf] = *(s16x8*)&us[5120 + row * 40 + lhi * 8];
            }
            #pragma unroll
            for (int nf = 0; nf < 4; ++nf) {
                const int rowb = wn * 64 + nf * 16 + llo;
                s16x8 bh = *(s16x8*)&us[10240 + rowb * 40 + lhi * 8];
                s16x8 bl = *(s16x8*)&us[15360 + rowb * 40 + lhi * 8];
                #pragma unroll
                for (int mf = 0; mf < 2; ++mf) {
                    acc[mf][nf] = __builtin_amdgcn_mfma_f32_16x16x32_bf16(ah[mf], bh, acc[mf][nf], 0, 0, 0);
                    acc[mf][nf] = __builtin_amdgcn_mfma_f32_16x16x32_bf16(ah[mf], bl, acc[mf][nf], 0, 0, 0);
                    acc[mf][nf] = __builtin_amdgcn_mfma_f32_16x16x32_bf16(al[mf], bh, acc[mf][nf], 0, 0, 0);
                }
            }
        }

        if (kt == 31) {
            for (int c = 0; c < 2; ++c) {
                __syncthreads();
                if (wn == c) {
                    #pragma unroll
                    for (int nf = 0; nf < 4; ++nf) {
                        const int colh = nf * 16 + llo;
                        const int tlc = colh >> 5, d = colh & 31;
                        const float bias = enc_b[chf * 512 + nt * 128 + c * 64 + colh];
                        #pragma unroll
                        for (int mf = 0; mf < 2; ++mf)
                            #pragma unroll
                            for (int r = 0; r < 4; ++r) {
                                const int m_local = mbase + mf * 16 + lhi * 4 + r;
                                float val = acc[mf][nf][r] + bias;
                                unsigned int u = __float_as_uint(val);
                                unsigned short hh = (unsigned short)(u >> 16);
                                const int tok = m_local * 2 + tlc;
                                us[tok * 40 + d] = hh;
                                us[10240 + tok * 40 + d] = bf16r(val - bf16f(hh));
                            }
                    }
                }
                __syncthreads();
                s16x8 fh[2], fl[2];
                #pragma unroll
                for (int gi = 0; gi < 2; ++gi) {
                    const int tokrow = (wid * 2 + gi) * 16 + llo;
                    fh[gi] = *(s16x8*)&us[tokrow * 40 + lhi * 8];
                    fl[gi] = *(s16x8*)&us[10240 + tokrow * 40 + lhi * 8];
                }
                float s1[2][4], s2[2][4]; int bj[2][4];
                #pragma unroll
                for (int gi = 0; gi < 2; ++gi)
                    #pragma unroll
                    for (int r = 0; r < 4; ++r) { s1[gi][r] = FLT_MAX; s2[gi][r] = FLT_MAX; bj[gi][r] = 0; }
                for (int jb = 0; jb < 16; ++jb) {
                    const int j = jb * 16 + llo;
                    s16x8 ch = *(s16x8*)&us[20480 + j * 40 + lhi * 8];
                    s16x8 cl = *(s16x8*)&us[30720 + j * 40 + lhi * 8];
                    const float cnv = *(const float*)&us[20480 + j * 40 + 32];
                    #pragma unroll
                    for (int gi = 0; gi < 2; ++gi) {
                        f32x4 sc = (f32x4)0.f;
                        sc = __builtin_amdgcn_mfma_f32_16x16x32_bf16(fh[gi], ch, sc, 0, 0, 0);
                        sc = __builtin_amdgcn_mfma_f32_16x16x32_bf16(fh[gi], cl, sc, 0, 0, 0);
                        sc = __builtin_amdgcn_mfma_f32_16x16x32_bf16(fl[gi], ch, sc, 0, 0, 0);
                        #pragma unroll
                        for (int r = 0; r < 4; ++r) {
                            float s = fmaf(-2.f, sc[r], cnv);
                            if (s < s1[gi][r])      { s2[gi][r] = s1[gi][r]; s1[gi][r] = s; bj[gi][r] = j; }
                            else if (s < s2[gi][r]) { s2[gi][r] = s; }
                        }
                    }
                }
                #pragma unroll
                for (int gi = 0; gi < 2; ++gi) {
                    float Fp = 0.f;
                    #pragma unroll
                    for (int e = 0; e < 8; ++e) {
                        float fv = bf16f((unsigned short)fh[gi][e]) + bf16f((unsigned short)fl[gi][e]);
                        Fp = fmaf(fv, fv, Fp);
                    }
                    Fp += __shfl_xor(Fp, 16);
                    Fp += __shfl_xor(Fp, 32);
                    #pragma unroll
                    for (int r = 0; r < 4; ++r) {
                        float a1 = s1[gi][r], a2 = s2[gi][r]; int aj = bj[gi][r];
                        #pragma unroll
                        for (int off = 1; off <= 8; off <<= 1) {
                            float o1 = __shfl_xor(a1, off);
                            float o2 = __shfl_xor(a2, off);
                            int   oj = __shfl_xor(aj, off);
                            if (o1 < a1) { a2 = fminf(a1, o2); a1 = o1; aj = oj; }
                            else         { a2 = fminf(o1, a2); }
                        }
                        const float Ft = __shfl(Fp, lhi * 4 + r);
                        if (llo == 0) {
                            const int tok_local = (wid * 2 + gi) * 16 + lhi * 4 + r;
                            const int row = tok_local >> 1, tlc2 = tok_local & 1;
                            const int t = chf * 16 + nt * 4 + c * 2 + tlc2;
                            float cv = (a2 - a1 < TAU) ? (float)(aj + 512) : (float)aj;
                            out[OUT_CODES_OFF + (size_t)(r0 + row) * 32 + t] = cv;
                            vq_local += Ft + a1;
                        }
                    }
                }
            }
        }
    }
    {
        float v = vq_local;
        #pragma unroll
        for (int off = 32; off >= 1; off >>= 1) v += __shfl_xor(v, off);
        if (lane == 0) atomicAdd(&out[OUT_LOSS_OFF], v * (1.25f * INV_N));
    }
}

// ============ Kernel F: wave-cooperative faithful numpy-f32 fixup (bit-identical) ===
__launch_bounds__(256)
__global__ void k_fix(const float* __restrict__ skills,
                      const float* __restrict__ enc_w,
                      const float* __restrict__ enc_b,
                      const float* __restrict__ cb_g,
                      float* __restrict__ codes)
{
    __shared__ unsigned int cnt;
    __shared__ unsigned short list[256];

    const int tid = threadIdx.x;
    const int base = blockIdx.x * 256;

    if (tid == 0) cnt = 0;
    __syncthreads();
    {
        const int c = (int)codes[base + tid];
        if (c >= 512) {
            unsigned int ix = atomicAdd(&cnt, 1u);
            list[ix] = (unsigned short)tid;
        }
    }
    __syncthreads();
    const unsigned int n = cnt;
    if (n == 0) return;

    const int wv = tid >> 6, lane = tid & 63;
    const int d = lane & 31;

    for (unsigned int i = wv; i < n; i += 4) {
        const int tok = base + (int)list[i];
        const int row = tok >> 5;
        const int t   = tok & 31;

        const float4* s4 = (const float4*)&skills[(size_t)row * 1024];
        const float4* w4 = (const float4*)&enc_w[(size_t)(t * 32 + d) * 1024];
        float v1 = 0.f, v2 = 0.f, v3 = 0.f;
        for (int q = 0; q < 96; ++q) {
            float4 a = s4[q], b = w4[q];
            v1 = fmaf(a.x, b.x, v1); v1 = fmaf(a.y, b.y, v1);
            v1 = fmaf(a.z, b.z, v1); v1 = fmaf(a.w, b.w, v1);
        }
        for (int q = 96; q < 192; ++q) {
            float4 a = s4[q], b = w4[q];
            v2 = fmaf(a.x, b.x, v2); v2 = fmaf(a.y, b.y, v2);
            v2 = fmaf(a.z, b.z, v2); v2 = fmaf(a.w, b.w, v2);
        }
        for (int q = 192; q < 256; ++q) {
            float4 a = s4[q], b = w4[q];
            v3 = fmaf(a.x, b.x, v3); v3 = fmaf(a.y, b.y, v3);
            v3 = fmaf(a.z, b.z, v3); v3 = fmaf(a.w, b.w, v3);
        }
        const float pd = ((v1 + v2) + v3) + enc_b[t * 32 + d];

        float pv[32];
        #pragma unroll
        for (int dd = 0; dd < 32; ++dd) pv[dd] = __shfl(pd, dd);

        float F;
        {
            float s[32];
            #pragma unroll
            for (int dd = 0; dd < 32; ++dd) s[dd] = pv[dd] * pv[dd];
            float r[8];
            #pragma unroll
            for (int j = 0; j < 8; ++j) r[j] = ((s[j] + s[8+j]) + s[16+j]) + s[24+j];
            F = ((r[0] + r[1]) + (r[2] + r[3])) + ((r[4] + r[5]) + (r[6] + r[7]));
        }

        float bs = FLT_MAX; int bj = 0;
        for (int m = 0; m < 4; ++m) {
            const int j = m * 64 + lane;
            const float* cj = &cb_g[j * 32];
            float g = 0.f;
            #pragma unroll
            for (int dd = 0; dd < 32; ++dd) g = fmaf(pv[dd], cj[dd], g);
            float cs[32];
            #pragma unroll
            for (int dd = 0; dd < 32; ++dd) cs[dd] = cj[dd] * cj[dd];
            float r[8];
            #pragma unroll
            for (int jj = 0; jj < 8; ++jj) r[jj] = ((cs[jj] + cs[8+jj]) + cs[16+jj]) + cs[24+jj];
            float cn = ((r[0] + r[1]) + (r[2] + r[3])) + ((r[4] + r[5]) + (r[6] + r[7]));
            float dist = (F - 2.0f * g) + cn;
            if (dist < bs) { bs = dist; bj = j; }
        }
        #pragma unroll
        for (int off = 32; off >= 1; off >>= 1) {
            float os = __shfl_xor(bs, off);
            int   oj = __shfl_xor(bj, off);
            if (os < bs || (os == bs && oj < bj)) { bs = os; bj = oj; }
        }
        if (lane == 0) codes[tok] = (float)bj;
    }
}

// ============ Kernel B: bf16 MFMA GEMM2, 2 t-steps per phase (R20, proven) ==========
template <bool PRED>
__launch_bounds__(512)
__global__ void k_dec(const float* __restrict__ skills,
                      const float* __restrict__ cb_g,
                      const unsigned short* __restrict__ cbb,
                      const float* __restrict__ dec_w,
                      const unsigned short* __restrict__ dwb,
                      const float* __restrict__ dec_b,
                      const float* __restrict__ codes,
                      float* __restrict__ recon,
                      float* __restrict__ loss_out)
{
    __shared__ unsigned short Qt[2][128][40], Wt[2][128][40];   // 40 KB

    const int tid = threadIdx.x;
    const int r0 = (blockIdx.x >> 3) * 128;
    const int n0 = (blockIdx.x & 7) * 128;
    const int wid = tid >> 6, lane = tid & 63;
    const int wm = wid >> 1, wn = wid & 1;
    const int mbase = wm * 32, nbase = wn * 64;
    const int lhi = lane >> 4, llo = lane & 15;
    const int srow = tid >> 2, sq = tid & 3;

    f32x4 acc[2][4];
    #pragma unroll
    for (int mf = 0; mf < 2; ++mf)
        #pragma unroll
        for (int nf = 0; nf < 4; ++nf) acc[mf][nf] = (f32x4)0.f;

    s16x8 q16[2], w16[2];
    float4 q0[2], q1[2], w0[2], w1[2];

    #pragma unroll
    for (int ph = 0; ph < 2; ++ph) {
        const int cc = ((int)codes[(size_t)(r0 + srow) * 32 + ph]) & 255;
        if (PRED) {
            q16[ph] = *(const s16x8*)(cbb + cc * 32 + sq * 8);
            w16[ph] = *(const s16x8*)(dwb + (size_t)(n0 + srow) * 1024 + ph * 32 + sq * 8);
        } else {
            const float* cp = &cb_g[cc * 32 + sq * 8];
            q0[ph] = *(const float4*)cp; q1[ph] = *(const float4*)(cp + 4);
            const float* wp = &dec_w[(size_t)(n0 + srow) * 1024 + ph * 32 + sq * 8];
            w0[ph] = *(const float4*)wp; w1[ph] = *(const float4*)(wp + 4);
        }
    }

    for (int tt = 0; tt < 16; ++tt) {
        __syncthreads();
        #pragma unroll
        for (int ph = 0; ph < 2; ++ph) {
            if (PRED) {
                *(s16x8*)&Qt[ph][srow][sq * 8] = q16[ph];
                *(s16x8*)&Wt[ph][srow][sq * 8] = w16[ph];
            } else {
                float xs[8] = {q0[ph].x, q0[ph].y, q0[ph].z, q0[ph].w,
                               q1[ph].x, q1[ph].y, q1[ph].z, q1[ph].w};
                s16x8 h;
                #pragma unroll
                for (int e = 0; e < 8; ++e) h[e] = (short)bf16r(xs[e]);
                *(s16x8*)&Qt[ph][srow][sq * 8] = h;
                float ys[8] = {w0[ph].x, w0[ph].y, w0[ph].z, w0[ph].w,
                               w1[ph].x, w1[ph].y, w1[ph].z, w1[ph].w};
                #pragma unroll
                for (int e = 0; e < 8; ++e) h[e] = (short)bf16r(ys[e]);
                *(s16x8*)&Wt[ph][srow][sq * 8] = h;
            }
        }
        __syncthreads();
        if (tt < 15) {
            #pragma unroll
            for (int ph = 0; ph < 2; ++ph) {
                const int tn = tt * 2 + 2 + ph;
                const int cc = ((int)codes[(size_t)(r0 + srow) * 32 + tn]) & 255;
                if (PRED) {
                    q16[ph] = *(const s16x8*)(cbb + cc * 32 + sq * 8);
                    w16[ph] = *(const s16x8*)(dwb + (size_t)(n0 + srow) * 1024 + tn * 32 + sq * 8);
                } else {
                    const float* cp = &cb_g[cc * 32 + sq * 8];
                    q0[ph] = *(const float4*)cp; q1[ph] = *(const float4*)(cp + 4);
                    const float* wp = &dec_w[(size_t)(n0 + srow) * 1024 + tn * 32 + sq * 8];
                    w0[ph] = *(const float4*)wp; w1[ph] = *(const float4*)(wp + 4);
                }
            }
        }
        #pragma unroll
        for (int ph = 0; ph < 2; ++ph) {
            s16x8 aq[2], bw[4];
            #pragma unroll
            for (int mf = 0; mf < 2; ++mf)
                aq[mf] = *(s16x8*)&Qt[ph][mbase + mf * 16 + llo][lhi * 8];
            #pragma unroll
            for (int nf = 0; nf < 4; ++nf)
                bw[nf] = *(s16x8*)&Wt[ph][nbase + nf * 16 + llo][lhi * 8];
            #pragma unroll
            for (int mf = 0; mf < 2; ++mf)
                #pragma unroll
                for (int nf = 0; nf < 4; ++nf)
                    acc[mf][nf] = __builtin_amdgcn_mfma_f32_16x16x32_bf16(aq[mf], bw[nf], acc[mf][nf], 0, 0, 0);
        }
    }

    float lsum = 0.f;
    #pragma unroll
    for (int mf = 0; mf < 2; ++mf)
        #pragma unroll
        for (int nf = 0; nf < 4; ++nf) {
            const int col = n0 + nbase + nf * 16 + llo;
            const float bias = dec_b[col];
            #pragma unroll
            for (int r = 0; r < 4; ++r) {
                const int row = r0 + mbase + mf * 16 + lhi * 4 + r;
                float rv = acc[mf][nf][r] + bias;
                float dv = rv - skills[(size_t)row * 1024 + col];
                lsum = fmaf(dv, dv, lsum);
                recon[(size_t)row * 1024 + col] = rv;
            }
        }
    #pragma unroll
    for (int off = 32; off >= 1; off >>= 1) lsum += __shfl_xor(lsum, off);
    if (lane == 0) atomicAdd(loss_out, lsum * INV_N);
}

extern "C" void kernel_launch(void* const* d_in, const int* in_sizes, int n_in,
                              void* d_out, int out_size, void* d_ws, size_t ws_size,
                              hipStream_t stream)
{
    const float* skills = (const float*)d_in[0];
    const float* enc_w  = (const float*)d_in[1];
    const float* enc_b  = (const float*)d_in[2];
    const float* cbg    = (const float*)d_in[3];
    const float* dec_w  = (const float*)d_in[4];
    const float* dec_b  = (const float*)d_in[5];
    float* out = (float*)d_out;

    hipMemsetAsync(out + OUT_LOSS_OFF, 0, 4, stream);

    // ws layout (big path): B-tiles 4MB | dwb 2MB | cbb 16KB
    const size_t NEED_BIG = 4UL*1024*1024 + 2097152UL + 16384UL + 256UL;
    unsigned short* wsu16 = (unsigned short*)d_ws;

    if (ws_size >= NEED_BIG) {
        unsigned short* Btl = wsu16;                    // 2097152 u16
        unsigned short* dwb = wsu16 + 2097152UL;        // 1048576 u16
        unsigned short* cbb = wsu16 + 3145728UL;        // 8192 u16
        unsigned short* Atl = (unsigned short*)out;     // recon region: exactly 128 MiB

        k_prep_all<<<dim3(8706), dim3(512), 0, stream>>>(skills, Atl, enc_w, Btl,
                                                         dec_w, dwb, cbg, cbb);
        k_enc_gl<<<dim3(512), dim3(512), 0, stream>>>(Atl, Btl, enc_b, cbg, out);
        k_fix<<<dim3(4096), dim3(256), 0, stream>>>(skills, enc_w, enc_b, cbg, out + OUT_CODES_OFF);
        k_dec<true><<<dim3(2048), dim3(512), 0, stream>>>(skills, cbg, cbb, dec_w, dwb, dec_b,
                                                          out + OUT_CODES_OFF, out, out + OUT_LOSS_OFF);
    } else {
        k_enc_fb<<<dim3(512), dim3(512), 0, stream>>>(skills, enc_w, enc_b, cbg, out);
        k_fix<<<dim3(4096), dim3(256), 0, stream>>>(skills, enc_w, enc_b, cbg, out + OUT_CODES_OFF);
        const bool pred = (ws_size >= (2097152UL + 16384UL + 64UL));
        unsigned short* dwb = wsu16;
        unsigned short* cbb = wsu16 + 1048576UL;
        if (pred) {
            k_prep_r<<<dim3(512), dim3(256), 0, stream>>>(dec_w, dwb, 131072);
            k_prep_r<<<dim3(4), dim3(256), 0, stream>>>(cbg, cbb, 1024);
            k_dec<true><<<dim3(2048), dim3(512), 0, stream>>>(skills, cbg, cbb, dec_w, dwb, dec_b,
                                                              out + OUT_CODES_OFF, out, out + OUT_LOSS_OFF);
        } else {
            k_dec<false><<<dim3(2048), dim3(512), 0, stream>>>(skills, cbg, cbb, dec_w, dwb, dec_b,
                                                               out + OUT_CODES_OFF, out, out + OUT_LOSS_OFF);
        }
    }
}